// Round 1
// baseline (346.741 us; speedup 1.0000x reference)
//
#include <hip/hip_runtime.h>

// ---------------- shared geometry ----------------
#define TW   128
#define TH   32
#define HALO 5
#define TIW  (TW + 2*HALO)   // 138
#define TIH  (TH + 2*HALO)   // 42
#define TB_P 144             // byte row stride for tb (padding)
#define VS_P 142             // u16 row stride for vs
#define NBX  8
#define NBY  32
#define NBZ  16
#define NB   (NBX*NBY*NBZ)   // 4096 blocks (both paths' partial count)
#define NPIX 16777216.0      // 16*1024*1024

#define CODE_BYTES (16u*1024u*1024u)  // 1 byte per pixel: t | (edge<<1)
#define NB2 4096                       // loss_stream grid (== NB so finalize is shared)

// ============================================================================
// K1: edge/code kernel — tile+halo staging, vertical column sums, horizontal
// sliding box sum, write per-pixel code byte (t | e<<1). Coalesced uint stores.
// ============================================================================
__global__ __launch_bounds__(256)
void edge_code(const int* __restrict__ target, unsigned char* __restrict__ code) {
    __shared__ unsigned char  tb[TIH][TB_P];
    __shared__ unsigned short vs[TH][VS_P];

    const int tid   = threadIdx.x;
    const int tileX = blockIdx.x * TW;
    const int tileY = blockIdx.y * TH;
    const int b     = blockIdx.z;

    const int* tgt = target + (size_t)b * (1024 * 1024);

    // ---- stage target tile + halo into LDS (zeros outside image) ----
    for (int idx = tid; idx < TIH * TIW; idx += 256) {
        int rr = idx / TIW;
        int cc = idx - rr * TIW;
        int gr = tileY + rr - HALO;
        int gc = tileX + cc - HALO;
        unsigned char v = 0;
        if ((unsigned)gr < 1024u && (unsigned)gc < 1024u)
            v = (unsigned char)tgt[gr * 1024 + gc];
        tb[rr][cc] = v;
    }
    __syncthreads();

    // ---- vertical sliding column sums over 11 rows ----
    if (tid < TIW) {
        int acc = 0;
        #pragma unroll
        for (int rr = 0; rr < 11; ++rr) acc += tb[rr][tid];
        vs[0][tid] = (unsigned short)acc;
        for (int r = 1; r < TH; ++r) {
            acc += (int)tb[r + 10][tid] - (int)tb[r - 1][tid];
            vs[r][tid] = (unsigned short)acc;
        }
    }
    __syncthreads();

    // ---- per-pixel edge predicate + code write ----
    const int tx = tid & 31;   // 32 threads * 4 cols = 128
    const int ty = tid >> 5;   // 8 rows per pass, 4 passes
    unsigned char* cb = code + (size_t)b * (1024 * 1024);

    #pragma unroll
    for (int p = 0; p < 4; ++p) {
        const int r  = ty + p * 8;
        const int gr = tileY + r;
        const int c0 = tx * 4;
        const int gc = tileX + c0;

        int S[4];
        int s = 0;
        #pragma unroll
        for (int k = 0; k < 11; ++k) s += vs[r][c0 + k];
        S[0] = s;
        #pragma unroll
        for (int j = 1; j < 4; ++j) {
            s += (int)vs[r][c0 + 10 + j] - (int)vs[r][c0 + j - 1];
            S[j] = s;
        }

        unsigned int w = 0;
        #pragma unroll
        for (int j = 0; j < 4; ++j) {
            const int t = tb[r + 5][c0 + 5 + j];
            const unsigned int e = (S[j] != 121 * t) ? 1u : 0u;
            w |= (((unsigned int)t) | (e << 1)) << (8 * j);
        }
        *(unsigned int*)(cb + (size_t)gr * 1024 + gc) = w;
    }
}

// ============================================================================
// K2: pure streaming loss kernel — no LDS staging, no mid-kernel barriers.
// Each thread: 4 iterations x 4 pixels, 2x unrolled so 8 float4 + 2 u32
// loads are in flight before dependent compute.
// ============================================================================
__device__ __forceinline__ void proc4(unsigned int cw,
                                      float4 x0, float4 x1, float4 y0, float4 y1,
                                      float& cnt, float& a1, float& a2,
                                      float& b1, float& b2) {
    float p0a[4] = {x0.x, x0.y, x0.z, x0.w};
    float p1a[4] = {x1.x, x1.y, x1.z, x1.w};
    float q0a[4] = {y0.x, y0.y, y0.z, y0.w};
    float q1a[4] = {y1.x, y1.y, y1.z, y1.w};
    #pragma unroll
    for (int j = 0; j < 4; ++j) {
        const unsigned int cbyte = (cw >> (8 * j)) & 0xffu;
        const int   t = (int)(cbyte & 1u);
        const float e = (float)((cbyte >> 1) & 1u);
        cnt += e;
        {   // score0
            float p0 = p0a[j], p1 = p1a[j];
            float m   = fmaxf(p0, p1);
            float lse = m + __logf(1.0f + __expf(-fabsf(p0 - p1)));
            float lpt = (t ? p1 : p0) - lse;
            float slp = p0 + p1 - 2.0f * lse;
            a1 += lpt;
            a2 += e * (slp - 1.5f * lpt);
        }
        {   // score1
            float q0 = q0a[j], q1 = q1a[j];
            float m   = fmaxf(q0, q1);
            float lse = m + __logf(1.0f + __expf(-fabsf(q0 - q1)));
            float lpt = (t ? q1 : q0) - lse;
            float slp = q0 + q1 - 2.0f * lse;
            b1 += lpt;
            b2 += e * (slp - 1.5f * lpt);
        }
    }
}

__global__ __launch_bounds__(256)
void loss_stream(const float* __restrict__ score0,
                 const float* __restrict__ score1,
                 const unsigned char* __restrict__ code,
                 float* __restrict__ partials) {
    __shared__ float red[4][5];
    const int tid = threadIdx.x;
    const int bid = blockIdx.x;

    // linear pixel index of this thread's first 4-pixel group
    const size_t P0 = 4u * (size_t)(bid * 256 + tid);     // < 4,194,304
    const int    b0 = (int)(P0 >> 20);                    // batch of first group
    const size_t rr = P0 & 1048575u;                      // offset within plane
    const float* s0p = score0 + (size_t)b0 * 2097152u + rr;
    const float* s1p = score1 + (size_t)b0 * 2097152u + rr;
    const unsigned int* cp = (const unsigned int*)(code + P0);

    // per-iteration strides: pixel index advances by 4*NB2*256 = 4,194,304
    // => batch advances by 4 => float offset += 4*2,097,152; code words += 1,048,576
    float cnt = 0.f, a1 = 0.f, a2 = 0.f, b1 = 0.f, b2 = 0.f;

    #pragma unroll
    for (int i = 0; i < 4; i += 2) {
        const size_t fA = (size_t)i       * 8388608u;
        const size_t fB = (size_t)(i + 1) * 8388608u;
        const unsigned int cwA = cp[(size_t)i       * 1048576u];
        const unsigned int cwB = cp[(size_t)(i + 1) * 1048576u];
        float4 xA0 = *(const float4*)(s0p + fA);
        float4 xA1 = *(const float4*)(s0p + fA + 1048576u);
        float4 yA0 = *(const float4*)(s1p + fA);
        float4 yA1 = *(const float4*)(s1p + fA + 1048576u);
        float4 xB0 = *(const float4*)(s0p + fB);
        float4 xB1 = *(const float4*)(s0p + fB + 1048576u);
        float4 yB0 = *(const float4*)(s1p + fB);
        float4 yB1 = *(const float4*)(s1p + fB + 1048576u);
        proc4(cwA, xA0, xA1, yA0, yA1, cnt, a1, a2, b1, b2);
        proc4(cwB, xB0, xB1, yB0, yB1, cnt, a1, a2, b1, b2);
    }

    float vals[5] = {cnt, a1, a2, b1, b2};
    const int lane = tid & 63, wv = tid >> 6;
    #pragma unroll
    for (int q = 0; q < 5; ++q) {
        float v = vals[q];
        #pragma unroll
        for (int off = 32; off > 0; off >>= 1) v += __shfl_down(v, off);
        if (lane == 0) red[wv][q] = v;
    }
    __syncthreads();
    if (tid == 0) {
        #pragma unroll
        for (int q = 0; q < 5; ++q)
            partials[q * NB2 + bid] = red[0][q] + red[1][q] + red[2][q] + red[3][q];
    }
}

// ============================================================================
// Fallback: original fused kernel (used only if ws_size is too small for the
// 16 MiB code array). Identical to the verified baseline.
// ============================================================================
__global__ __launch_bounds__(256)
void fused_edge_loss(const float* __restrict__ score0,
                     const float* __restrict__ score1,
                     const int*   __restrict__ target,
                     float*       __restrict__ ws) {
    __shared__ unsigned char  tb[TIH][TB_P];
    __shared__ unsigned short vs[TH][VS_P];
    __shared__ float          red[4][5];

    const int tid   = threadIdx.x;
    const int tileX = blockIdx.x * TW;
    const int tileY = blockIdx.y * TH;
    const int b     = blockIdx.z;
    const int bid   = (blockIdx.z * NBY + blockIdx.y) * NBX + blockIdx.x;

    const int* tgt = target + (size_t)b * (1024 * 1024);

    for (int idx = tid; idx < TIH * TIW; idx += 256) {
        int rr = idx / TIW;
        int cc = idx - rr * TIW;
        int gr = tileY + rr - HALO;
        int gc = tileX + cc - HALO;
        unsigned char v = 0;
        if ((unsigned)gr < 1024u && (unsigned)gc < 1024u)
            v = (unsigned char)tgt[gr * 1024 + gc];
        tb[rr][cc] = v;
    }
    __syncthreads();

    if (tid < TIW) {
        int acc = 0;
        #pragma unroll
        for (int rr = 0; rr < 11; ++rr) acc += tb[rr][tid];
        vs[0][tid] = (unsigned short)acc;
        for (int r = 1; r < TH; ++r) {
            acc += (int)tb[r + 10][tid] - (int)tb[r - 1][tid];
            vs[r][tid] = (unsigned short)acc;
        }
    }
    __syncthreads();

    const float* s0b = score0 + (size_t)b * (2 * 1024 * 1024);
    const float* s1b = score1 + (size_t)b * (2 * 1024 * 1024);
    const int tx = tid & 31;
    const int ty = tid >> 5;

    float cnt = 0.f, a1 = 0.f, a2 = 0.f, b1 = 0.f, b2 = 0.f;

    #pragma unroll
    for (int p = 0; p < 4; ++p) {
        const int r  = ty + p * 8;
        const int gr = tileY + r;
        const int c0 = tx * 4;
        const int gc = tileX + c0;

        int S[4];
        int s = 0;
        #pragma unroll
        for (int k = 0; k < 11; ++k) s += vs[r][c0 + k];
        S[0] = s;
        #pragma unroll
        for (int j = 1; j < 4; ++j) {
            s += (int)vs[r][c0 + 10 + j] - (int)vs[r][c0 + j - 1];
            S[j] = s;
        }

        const size_t base = (size_t)gr * 1024 + gc;
        float4 x0 = *(const float4*)(s0b + base);
        float4 x1 = *(const float4*)(s0b + 1048576 + base);
        float4 y0 = *(const float4*)(s1b + base);
        float4 y1 = *(const float4*)(s1b + 1048576 + base);
        float p0a[4] = {x0.x, x0.y, x0.z, x0.w};
        float p1a[4] = {x1.x, x1.y, x1.z, x1.w};
        float q0a[4] = {y0.x, y0.y, y0.z, y0.w};
        float q1a[4] = {y1.x, y1.y, y1.z, y1.w};

        #pragma unroll
        for (int j = 0; j < 4; ++j) {
            const int t = tb[r + 5][c0 + 5 + j];
            const float e = (S[j] != 121 * t) ? 1.0f : 0.0f;
            cnt += e;
            {
                float p0 = p0a[j], p1 = p1a[j];
                float m   = fmaxf(p0, p1);
                float lse = m + __logf(1.0f + __expf(-fabsf(p0 - p1)));
                float lpt = (t ? p1 : p0) - lse;
                float slp = p0 + p1 - 2.0f * lse;
                a1 += lpt;
                a2 += e * (slp - 1.5f * lpt);
            }
            {
                float q0 = q0a[j], q1 = q1a[j];
                float m   = fmaxf(q0, q1);
                float lse = m + __logf(1.0f + __expf(-fabsf(q0 - q1)));
                float lpt = (t ? q1 : q0) - lse;
                float slp = q0 + q1 - 2.0f * lse;
                b1 += lpt;
                b2 += e * (slp - 1.5f * lpt);
            }
        }
    }

    float vals[5] = {cnt, a1, a2, b1, b2};
    const int lane = tid & 63, wv = tid >> 6;
    #pragma unroll
    for (int q = 0; q < 5; ++q) {
        float v = vals[q];
        #pragma unroll
        for (int off = 32; off > 0; off >>= 1) v += __shfl_down(v, off);
        if (lane == 0) red[wv][q] = v;
    }
    __syncthreads();
    if (tid == 0) {
        #pragma unroll
        for (int q = 0; q < 5; ++q) {
            float v = red[0][q] + red[1][q] + red[2][q] + red[3][q];
            ws[q * NB + bid] = v;
        }
    }
}

// ---------------- final reduction + scalar loss (shared by both paths) -----
__global__ __launch_bounds__(256)
void finalize_loss(const float* __restrict__ ws, float* __restrict__ out) {
    __shared__ double red[4][5];
    const int tid = threadIdx.x;
    double acc[5] = {0, 0, 0, 0, 0};
    for (int i = tid; i < NB; i += 256) {
        #pragma unroll
        for (int q = 0; q < 5; ++q) acc[q] += (double)ws[q * NB + i];
    }
    const int lane = tid & 63, wv = tid >> 6;
    #pragma unroll
    for (int q = 0; q < 5; ++q) {
        double v = acc[q];
        #pragma unroll
        for (int off = 32; off > 0; off >>= 1) v += __shfl_down(v, off);
        if (lane == 0) red[wv][q] = v;
    }
    __syncthreads();
    if (tid == 0) {
        double s[5];
        #pragma unroll
        for (int q = 0; q < 5; ++q)
            s[q] = red[0][q] + red[1][q] + red[2][q] + red[3][q];
        const double N = NPIX;
        double alpha = s[0] / N;
        if (alpha > 0.2) alpha = 0.2;
        double loss = (s[1] + alpha * s[2]) + 0.5 * (s[3] + alpha * s[4]);
        out[0] = (float)(-loss / N);
    }
}

extern "C" void kernel_launch(void* const* d_in, const int* in_sizes, int n_in,
                              void* d_out, int out_size, void* d_ws, size_t ws_size,
                              hipStream_t stream) {
    const float* score0 = (const float*)d_in[0];
    const float* score1 = (const float*)d_in[1];
    const int*   target = (const int*)d_in[2];
    float* out = (float*)d_out;
    unsigned char* ws = (unsigned char*)d_ws;

    const size_t need = (size_t)CODE_BYTES + (size_t)5 * NB2 * 4;
    if (ws_size >= need) {
        // Split path: edge/code pass + pure streaming loss pass.
        unsigned char* code     = ws;
        float*         partials = (float*)(ws + CODE_BYTES);
        dim3 g1(NBX, NBY, NBZ);
        edge_code<<<g1, 256, 0, stream>>>(target, code);
        loss_stream<<<NB2, 256, 0, stream>>>(score0, score1, code, partials);
        finalize_loss<<<1, 256, 0, stream>>>(partials, out);
    } else {
        // Fallback: verified fused baseline (workspace too small for code array).
        float* partials = (float*)ws;
        dim3 grid(NBX, NBY, NBZ);
        fused_edge_loss<<<grid, 256, 0, stream>>>(score0, score1, target, partials);
        finalize_loss<<<1, 256, 0, stream>>>(partials, out);
    }
}

// Round 3
// 330.870 us; speedup vs baseline: 1.0480x; 1.0480x over previous
//
#include <hip/hip_runtime.h>

typedef float v2f __attribute__((ext_vector_type(2)));
typedef unsigned long long u64;

#define NPIX 16777216.0

// ---- workspace layout (split path) ----
#define TBITS_OFF 0u
#define EBITS_OFF (2u*1024u*1024u)          // t-bits: 2 MB
#define PART_OFF  (4u*1024u*1024u)          // e-bits: 2 MB
#define NB2       8192                      // loss_stream2 grid
// partials: 5*NB2*4 = 160 KB at PART_OFF

// ---- fallback (fused) geometry ----
#define TW   128
#define TH   32
#define HALO 5
#define TIW  (TW + 2*HALO)
#define TIH  (TH + 2*HALO)
#define TB_P 144
#define VS_P 142
#define NBX  8
#define NBY  32
#define NBZ  16
#define NB   (NBX*NBY*NBZ)

// ============================================================================
// K0: pack target (int32 0/1) into bit plane via wave ballot.
// 2048 blocks x 256 thr = 8192 waves; each wave packs 32 u64 words (2048 px).
// ============================================================================
__global__ __launch_bounds__(256)
void pack_bits(const int* __restrict__ target, u64* __restrict__ tbits) {
    const int gtid = blockIdx.x * 256 + threadIdx.x;
    const int wave = gtid >> 6;              // 0..8191
    const int lane = threadIdx.x & 63;
    #pragma unroll 2
    for (int i = 0; i < 32; i += 4) {
        const size_t w = (size_t)wave * 32 + i;
        const int v0 = target[((w + 0) << 6) | lane];
        const int v1 = target[((w + 1) << 6) | lane];
        const int v2 = target[((w + 2) << 6) | lane];
        const int v3 = target[((w + 3) << 6) | lane];
        const u64 m0 = __ballot(v0 != 0);
        const u64 m1 = __ballot(v1 != 0);
        const u64 m2 = __ballot(v2 != 0);
        const u64 m3 = __ballot(v3 != 0);
        if (lane == 0) {
            tbits[w + 0] = m0;
            tbits[w + 1] = m1;
            tbits[w + 2] = m2;
            tbits[w + 3] = m3;
        }
    }
}

// ============================================================================
// K1: edge bits. edge=1 iff 11x11 window (zero-padded) is non-constant,
// i.e. winOR != winAND (exactly the Laplacian != 0 predicate for 0/1 input).
// Separable: vertical OR/AND over 11 rows, then horizontal 11-window via
// 64-bit funnel shifts. One thread per (batch,row,word): 262144 threads.
// ============================================================================
__device__ __forceinline__ u64 hor11_or(u64 L, u64 M, u64 R) {
    u64 o = M;
    o |= (M >> 1) | (R << 63);
    o |= (M >> 2) | (R << 62);
    o |= (M >> 3) | (R << 61);
    o |= (M >> 4) | (R << 60);
    o |= (M >> 5) | (R << 59);
    o |= (M << 1) | (L >> 63);
    o |= (M << 2) | (L >> 62);
    o |= (M << 3) | (L >> 61);
    o |= (M << 4) | (L >> 60);
    o |= (M << 5) | (L >> 59);
    return o;
}
__device__ __forceinline__ u64 hor11_and(u64 L, u64 M, u64 R) {
    u64 a = M;
    a &= (M >> 1) | (R << 63);
    a &= (M >> 2) | (R << 62);
    a &= (M >> 3) | (R << 61);
    a &= (M >> 4) | (R << 60);
    a &= (M >> 5) | (R << 59);
    a &= (M << 1) | (L >> 63);
    a &= (M << 2) | (L >> 62);
    a &= (M << 3) | (L >> 61);
    a &= (M << 4) | (L >> 60);
    a &= (M << 5) | (L >> 59);
    return a;
}

__global__ __launch_bounds__(256)
void edge_bits(const u64* __restrict__ tbits, u64* __restrict__ ebits) {
    const int idx = blockIdx.x * 256 + threadIdx.x;   // 0..262143
    const int wi  = idx & 15;
    const int row = (idx >> 4) & 1023;
    const int b   = idx >> 14;
    const u64* plane = tbits + (size_t)b * 16384;

    u64 oL = 0, oM = 0, oR = 0;
    u64 aL = ~0ull, aM = ~0ull, aR = ~0ull;
    #pragma unroll
    for (int dr = -5; dr <= 5; ++dr) {
        const int r = row + dr;
        u64 L = 0, M = 0, R = 0;
        if ((unsigned)r < 1024u) {
            const u64* rp = plane + (size_t)r * 16;
            L = (wi > 0)  ? rp[wi - 1] : 0ull;
            M = rp[wi];
            R = (wi < 15) ? rp[wi + 1] : 0ull;
        }
        oL |= L; oM |= M; oR |= R;
        aL &= L; aM &= M; aR &= R;
    }
    const u64 O = hor11_or(oL, oM, oR);
    const u64 A = hor11_and(aL, aM, aR);
    ebits[idx] = O ^ A;
}

// ============================================================================
// K2: streaming loss. 8192 blocks x 256 thr; each thread: two 4-px groups
// (batches 0-7 and 8-15), all loads issued up front, float2-packed math.
// ============================================================================
__device__ __forceinline__ void acc_pair(v2f p0, v2f p1, unsigned t0, unsigned t1,
                                         v2f ef, v2f& s1, v2f& s2) {
    v2f d = p0 - p1;
    v2f sp;
    sp.x = __logf(1.0f + __expf(-fabsf(d.x)));
    sp.y = __logf(1.0f + __expf(-fabsf(d.y)));
    v2f m;
    m.x = fmaxf(p0.x, p1.x);
    m.y = fmaxf(p0.y, p1.y);
    v2f lse = m + sp;
    v2f pt;                          // exact select (no fma reassociation)
    pt.x = t0 ? p1.x : p0.x;
    pt.y = t1 ? p1.y : p0.y;
    v2f lpt = pt - lse;
    v2f slp = (p0 + p1) - 2.0f * lse;
    s1 += lpt;
    s2 += ef * (slp - 1.5f * lpt);
}

__device__ __forceinline__ void proc_group(float4 x0, float4 x1, float4 y0, float4 y1,
                                           unsigned nt, unsigned ne,
                                           v2f& cntv, v2f& a1, v2f& a2, v2f& b1, v2f& b2) {
    #pragma unroll
    for (int h = 0; h < 2; ++h) {
        const unsigned t0 = (nt >> (2 * h)) & 1u;
        const unsigned t1 = (nt >> (2 * h + 1)) & 1u;
        const unsigned e0 = (ne >> (2 * h)) & 1u;
        const unsigned e1 = (ne >> (2 * h + 1)) & 1u;
        v2f ef; ef.x = (float)e0; ef.y = (float)e1;
        cntv += ef;
        v2f p0, p1, q0, q1;
        p0.x = h ? x0.z : x0.x;  p0.y = h ? x0.w : x0.y;
        p1.x = h ? x1.z : x1.x;  p1.y = h ? x1.w : x1.y;
        q0.x = h ? y0.z : y0.x;  q0.y = h ? y0.w : y0.y;
        q1.x = h ? y1.z : y1.x;  q1.y = h ? y1.w : y1.y;
        acc_pair(p0, p1, t0, t1, ef, a1, a2);
        acc_pair(q0, q1, t0, t1, ef, b1, b2);
    }
}

__global__ __launch_bounds__(256)
void loss_stream2(const float* __restrict__ score0,
                  const float* __restrict__ score1,
                  const unsigned int* __restrict__ tb32,
                  const unsigned int* __restrict__ eb32,
                  float* __restrict__ partials) {
    __shared__ float red[4][5];
    const int tid = threadIdx.x;
    const int bid = blockIdx.x;
    const int g   = bid * 256 + tid;                 // 0..2097151

    const size_t PA = 4ull * (size_t)g;              // batches 0..7
    const size_t PB = PA + 8388608ull;               // batches 8..15

    const float* pA0 = score0 + (PA >> 20) * 2097152u + (PA & 1048575u);
    const float* pA1 = score1 + (PA >> 20) * 2097152u + (PA & 1048575u);
    const float* pB0 = score0 + (PB >> 20) * 2097152u + (PB & 1048575u);
    const float* pB1 = score1 + (PB >> 20) * 2097152u + (PB & 1048575u);

    // ---- one load burst: 8x float4 + 4x u32 ----
    const float4 xA0 = *(const float4*)(pA0);
    const float4 xA1 = *(const float4*)(pA0 + 1048576);
    const float4 yA0 = *(const float4*)(pA1);
    const float4 yA1 = *(const float4*)(pA1 + 1048576);
    const float4 xB0 = *(const float4*)(pB0);
    const float4 xB1 = *(const float4*)(pB0 + 1048576);
    const float4 yB0 = *(const float4*)(pB1);
    const float4 yB1 = *(const float4*)(pB1 + 1048576);
    const unsigned twA = tb32[PA >> 5], ewA = eb32[PA >> 5];
    const unsigned twB = tb32[PB >> 5], ewB = eb32[PB >> 5];

    const unsigned shA = (unsigned)PA & 31u;
    const unsigned shB = (unsigned)PB & 31u;
    const unsigned ntA = (twA >> shA) & 15u, neA = (ewA >> shA) & 15u;
    const unsigned ntB = (twB >> shB) & 15u, neB = (ewB >> shB) & 15u;

    v2f cntv = {0.f, 0.f}, a1 = {0.f, 0.f}, a2 = {0.f, 0.f};
    v2f b1 = {0.f, 0.f}, b2 = {0.f, 0.f};
    proc_group(xA0, xA1, yA0, yA1, ntA, neA, cntv, a1, a2, b1, b2);
    proc_group(xB0, xB1, yB0, yB1, ntB, neB, cntv, a1, a2, b1, b2);

    float vals[5] = {cntv.x + cntv.y, a1.x + a1.y, a2.x + a2.y,
                     b1.x + b1.y, b2.x + b2.y};
    const int lane = tid & 63, wv = tid >> 6;
    #pragma unroll
    for (int q = 0; q < 5; ++q) {
        float v = vals[q];
        #pragma unroll
        for (int off = 32; off > 0; off >>= 1) v += __shfl_down(v, off);
        if (lane == 0) red[wv][q] = v;
    }
    __syncthreads();
    if (tid == 0) {
        #pragma unroll
        for (int q = 0; q < 5; ++q)
            partials[q * NB2 + bid] = red[0][q] + red[1][q] + red[2][q] + red[3][q];
    }
}

// ---------------- final reduction (n partial sets) ----------------
__global__ __launch_bounds__(1024)
void finalize_loss(const float* __restrict__ ws, float* __restrict__ out, int n) {
    __shared__ double red[16][5];
    const int tid = threadIdx.x;
    double acc[5] = {0, 0, 0, 0, 0};
    for (int i = tid; i < n; i += 1024) {
        #pragma unroll
        for (int q = 0; q < 5; ++q) acc[q] += (double)ws[q * n + i];
    }
    const int lane = tid & 63, wv = tid >> 6;
    #pragma unroll
    for (int q = 0; q < 5; ++q) {
        double v = acc[q];
        #pragma unroll
        for (int off = 32; off > 0; off >>= 1) v += __shfl_down(v, off);
        if (lane == 0) red[wv][q] = v;
    }
    __syncthreads();
    if (tid == 0) {
        double s[5];
        #pragma unroll
        for (int q = 0; q < 5; ++q) {
            double v = 0;
            for (int w = 0; w < 16; ++w) v += red[w][q];
            s[q] = v;
        }
        const double N = NPIX;
        double alpha = s[0] / N;
        if (alpha > 0.2) alpha = 0.2;
        double loss = (s[1] + alpha * s[2]) + 0.5 * (s[3] + alpha * s[4]);
        out[0] = (float)(-loss / N);
    }
}

// ============================================================================
// Fallback: verified fused baseline (workspace too small for bit planes).
// ============================================================================
__global__ __launch_bounds__(256)
void fused_edge_loss(const float* __restrict__ score0,
                     const float* __restrict__ score1,
                     const int*   __restrict__ target,
                     float*       __restrict__ ws) {
    __shared__ unsigned char  tb[TIH][TB_P];
    __shared__ unsigned short vs[TH][VS_P];
    __shared__ float          red[4][5];

    const int tid   = threadIdx.x;
    const int tileX = blockIdx.x * TW;
    const int tileY = blockIdx.y * TH;
    const int b     = blockIdx.z;
    const int bid   = (blockIdx.z * NBY + blockIdx.y) * NBX + blockIdx.x;

    const int* tgt = target + (size_t)b * (1024 * 1024);

    for (int idx = tid; idx < TIH * TIW; idx += 256) {
        int rr = idx / TIW;
        int cc = idx - rr * TIW;
        int gr = tileY + rr - HALO;
        int gc = tileX + cc - HALO;
        unsigned char v = 0;
        if ((unsigned)gr < 1024u && (unsigned)gc < 1024u)
            v = (unsigned char)tgt[gr * 1024 + gc];
        tb[rr][cc] = v;
    }
    __syncthreads();

    if (tid < TIW) {
        int acc = 0;
        #pragma unroll
        for (int rr = 0; rr < 11; ++rr) acc += tb[rr][tid];
        vs[0][tid] = (unsigned short)acc;
        for (int r = 1; r < TH; ++r) {
            acc += (int)tb[r + 10][tid] - (int)tb[r - 1][tid];
            vs[r][tid] = (unsigned short)acc;
        }
    }
    __syncthreads();

    const float* s0b = score0 + (size_t)b * (2 * 1024 * 1024);
    const float* s1b = score1 + (size_t)b * (2 * 1024 * 1024);
    const int tx = tid & 31;
    const int ty = tid >> 5;

    float cnt = 0.f, a1 = 0.f, a2 = 0.f, b1 = 0.f, b2 = 0.f;

    #pragma unroll
    for (int p = 0; p < 4; ++p) {
        const int r  = ty + p * 8;
        const int gr = tileY + r;
        const int c0 = tx * 4;
        const int gc = tileX + c0;

        int S[4];
        int s = 0;
        #pragma unroll
        for (int k = 0; k < 11; ++k) s += vs[r][c0 + k];
        S[0] = s;
        #pragma unroll
        for (int j = 1; j < 4; ++j) {
            s += (int)vs[r][c0 + 10 + j] - (int)vs[r][c0 + j - 1];
            S[j] = s;
        }

        const size_t base = (size_t)gr * 1024 + gc;
        float4 x0 = *(const float4*)(s0b + base);
        float4 x1 = *(const float4*)(s0b + 1048576 + base);
        float4 y0 = *(const float4*)(s1b + base);
        float4 y1 = *(const float4*)(s1b + 1048576 + base);
        float p0a[4] = {x0.x, x0.y, x0.z, x0.w};
        float p1a[4] = {x1.x, x1.y, x1.z, x1.w};
        float q0a[4] = {y0.x, y0.y, y0.z, y0.w};
        float q1a[4] = {y1.x, y1.y, y1.z, y1.w};

        #pragma unroll
        for (int j = 0; j < 4; ++j) {
            const int t = tb[r + 5][c0 + 5 + j];
            const float e = (S[j] != 121 * t) ? 1.0f : 0.0f;
            cnt += e;
            {
                float p0 = p0a[j], p1 = p1a[j];
                float m   = fmaxf(p0, p1);
                float lse = m + __logf(1.0f + __expf(-fabsf(p0 - p1)));
                float lpt = (t ? p1 : p0) - lse;
                float slp = p0 + p1 - 2.0f * lse;
                a1 += lpt;
                a2 += e * (slp - 1.5f * lpt);
            }
            {
                float q0 = q0a[j], q1 = q1a[j];
                float m   = fmaxf(q0, q1);
                float lse = m + __logf(1.0f + __expf(-fabsf(q0 - q1)));
                float lpt = (t ? q1 : q0) - lse;
                float slp = q0 + q1 - 2.0f * lse;
                b1 += lpt;
                b2 += e * (slp - 1.5f * lpt);
            }
        }
    }

    float vals[5] = {cnt, a1, a2, b1, b2};
    const int lane = tid & 63, wv = tid >> 6;
    #pragma unroll
    for (int q = 0; q < 5; ++q) {
        float v = vals[q];
        #pragma unroll
        for (int off = 32; off > 0; off >>= 1) v += __shfl_down(v, off);
        if (lane == 0) red[wv][q] = v;
    }
    __syncthreads();
    if (tid == 0) {
        #pragma unroll
        for (int q = 0; q < 5; ++q) {
            float v = red[0][q] + red[1][q] + red[2][q] + red[3][q];
            ws[q * NB + bid] = v;
        }
    }
}

extern "C" void kernel_launch(void* const* d_in, const int* in_sizes, int n_in,
                              void* d_out, int out_size, void* d_ws, size_t ws_size,
                              hipStream_t stream) {
    const float* score0 = (const float*)d_in[0];
    const float* score1 = (const float*)d_in[1];
    const int*   target = (const int*)d_in[2];
    float* out = (float*)d_out;
    unsigned char* ws = (unsigned char*)d_ws;

    const size_t need = (size_t)PART_OFF + (size_t)5 * NB2 * 4;  // 4 MB + 160 KB
    if (ws_size >= need) {
        u64* tb = (u64*)(ws + TBITS_OFF);
        u64* eb = (u64*)(ws + EBITS_OFF);
        float* partials = (float*)(ws + PART_OFF);
        pack_bits<<<2048, 256, 0, stream>>>(target, tb);
        edge_bits<<<1024, 256, 0, stream>>>(tb, eb);
        loss_stream2<<<NB2, 256, 0, stream>>>(score0, score1,
                                              (const unsigned int*)tb,
                                              (const unsigned int*)eb, partials);
        finalize_loss<<<1, 1024, 0, stream>>>(partials, out, NB2);
    } else {
        float* partials = (float*)ws;
        dim3 grid(NBX, NBY, NBZ);
        fused_edge_loss<<<grid, 256, 0, stream>>>(score0, score1, target, partials);
        finalize_loss<<<1, 1024, 0, stream>>>(partials, out, NB);
    }
}

// Round 4
// 328.567 us; speedup vs baseline: 1.0553x; 1.0070x over previous
//
#include <hip/hip_runtime.h>

typedef float v2f __attribute__((ext_vector_type(2)));
typedef unsigned long long u64;

#define NPIX 16777216.0

// ---- workspace layout (split path) ----
#define TBITS_OFF 0u
#define EBITS_OFF (2u*1024u*1024u)          // t-bits: 2 MB
#define PART_OFF  (4u*1024u*1024u)          // e-bits: 2 MB
#define NB3       4096                      // loss_stream3 grid
// partials: 5*NB3*4 = 80 KB at PART_OFF

// ---- fallback (fused) geometry ----
#define TW   128
#define TH   32
#define HALO 5
#define TIW  (TW + 2*HALO)
#define TIH  (TH + 2*HALO)
#define TB_P 144
#define VS_P 142
#define NBX  8
#define NBY  32
#define NBZ  16
#define NB   (NBX*NBY*NBZ)

// ============================================================================
// K0: pack target (int32 0/1) into bit plane. 32 px/thread: 8x int4 loads
// (128 B/lane in flight), local bit build, one coalesced u32 store.
// 2048 blocks x 256 threads = 524288 threads.
// ============================================================================
__device__ __forceinline__ unsigned nib(int4 r) {
    return (unsigned)((r.x & 1) | ((r.y & 1) << 1) | ((r.z & 1) << 2) | ((r.w & 1) << 3));
}

__global__ __launch_bounds__(256)
void pack_bits32(const int* __restrict__ target, unsigned int* __restrict__ tb32) {
    const int G = blockIdx.x * 256 + threadIdx.x;        // 0..524287
    const int4* p = (const int4*)target + (size_t)G * 8; // 32 consecutive int32
    const int4 r0 = p[0], r1 = p[1], r2 = p[2], r3 = p[3];
    const int4 r4 = p[4], r5 = p[5], r6 = p[6], r7 = p[7];
    unsigned m = nib(r0);
    m |= nib(r1) << 4;
    m |= nib(r2) << 8;
    m |= nib(r3) << 12;
    m |= nib(r4) << 16;
    m |= nib(r5) << 20;
    m |= nib(r6) << 24;
    m |= nib(r7) << 28;
    tb32[G] = m;   // u32 word G covers pixels [32G, 32G+32), little-endian bits
}

// ============================================================================
// K1: edge bits. edge=1 iff 11x11 window (zero-padded) is non-constant,
// i.e. winOR != winAND (== Laplacian != 0 for 0/1 input). Separable:
// vertical OR/AND over 11 rows, then horizontal 11-window via funnel shifts.
// One thread per (batch,row,word): 262144 threads.
// ============================================================================
__device__ __forceinline__ u64 hor11_or(u64 L, u64 M, u64 R) {
    u64 o = M;
    o |= (M >> 1) | (R << 63);
    o |= (M >> 2) | (R << 62);
    o |= (M >> 3) | (R << 61);
    o |= (M >> 4) | (R << 60);
    o |= (M >> 5) | (R << 59);
    o |= (M << 1) | (L >> 63);
    o |= (M << 2) | (L >> 62);
    o |= (M << 3) | (L >> 61);
    o |= (M << 4) | (L >> 60);
    o |= (M << 5) | (L >> 59);
    return o;
}
__device__ __forceinline__ u64 hor11_and(u64 L, u64 M, u64 R) {
    u64 a = M;
    a &= (M >> 1) | (R << 63);
    a &= (M >> 2) | (R << 62);
    a &= (M >> 3) | (R << 61);
    a &= (M >> 4) | (R << 60);
    a &= (M >> 5) | (R << 59);
    a &= (M << 1) | (L >> 63);
    a &= (M << 2) | (L >> 62);
    a &= (M << 3) | (L >> 61);
    a &= (M << 4) | (L >> 60);
    a &= (M << 5) | (L >> 59);
    return a;
}

__global__ __launch_bounds__(256)
void edge_bits(const u64* __restrict__ tbits, u64* __restrict__ ebits) {
    const int idx = blockIdx.x * 256 + threadIdx.x;   // 0..262143
    const int wi  = idx & 15;
    const int row = (idx >> 4) & 1023;
    const int b   = idx >> 14;
    const u64* plane = tbits + (size_t)b * 16384;

    u64 oL = 0, oM = 0, oR = 0;
    u64 aL = ~0ull, aM = ~0ull, aR = ~0ull;
    #pragma unroll
    for (int dr = -5; dr <= 5; ++dr) {
        const int r = row + dr;
        u64 L = 0, M = 0, R = 0;
        if ((unsigned)r < 1024u) {
            const u64* rp = plane + (size_t)r * 16;
            L = (wi > 0)  ? rp[wi - 1] : 0ull;
            M = rp[wi];
            R = (wi < 15) ? rp[wi + 1] : 0ull;
        }
        oL |= L; oM |= M; oR |= R;
        aL &= L; aM &= M; aR &= R;
    }
    const u64 O = hor11_or(oL, oM, oR);
    const u64 A = hor11_and(aL, aM, aR);
    ebits[idx] = O ^ A;
}

// ============================================================================
// K2: streaming loss, software-pipelined. 4096 blocks x 256 thr; each thread
// owns 4 groups of 4 px (one per batch quartet: P_k = 4g + k*4194304).
// Schedule L0,L1, C0,L2, C1,L3, C2, C3 keeps >=1 load burst outstanding for
// ~3/4 of the wave's life -> sustains memory-level parallelism during compute.
// ============================================================================
__device__ __forceinline__ void acc_pair(v2f p0, v2f p1, unsigned t0, unsigned t1,
                                         v2f ef, v2f& s1, v2f& s2) {
    v2f d = p0 - p1;
    v2f sp;
    sp.x = __logf(1.0f + __expf(-fabsf(d.x)));
    sp.y = __logf(1.0f + __expf(-fabsf(d.y)));
    v2f m;
    m.x = fmaxf(p0.x, p1.x);
    m.y = fmaxf(p0.y, p1.y);
    v2f lse = m + sp;
    v2f pt;                          // exact select (no fma reassociation)
    pt.x = t0 ? p1.x : p0.x;
    pt.y = t1 ? p1.y : p0.y;
    v2f lpt = pt - lse;
    v2f slp = (p0 + p1) - 2.0f * lse;
    s1 += lpt;
    s2 += ef * (slp - 1.5f * lpt);
}

__device__ __forceinline__ void proc_group(float4 x0, float4 x1, float4 y0, float4 y1,
                                           unsigned nt, unsigned ne,
                                           v2f& cntv, v2f& a1, v2f& a2, v2f& b1, v2f& b2) {
    #pragma unroll
    for (int h = 0; h < 2; ++h) {
        const unsigned t0 = (nt >> (2 * h)) & 1u;
        const unsigned t1 = (nt >> (2 * h + 1)) & 1u;
        const unsigned e0 = (ne >> (2 * h)) & 1u;
        const unsigned e1 = (ne >> (2 * h + 1)) & 1u;
        v2f ef; ef.x = (float)e0; ef.y = (float)e1;
        cntv += ef;
        v2f p0, p1, q0, q1;
        p0.x = h ? x0.z : x0.x;  p0.y = h ? x0.w : x0.y;
        p1.x = h ? x1.z : x1.x;  p1.y = h ? x1.w : x1.y;
        q0.x = h ? y0.z : y0.x;  q0.y = h ? y0.w : y0.y;
        q1.x = h ? y1.z : y1.x;  q1.y = h ? y1.w : y1.y;
        acc_pair(p0, p1, t0, t1, ef, a1, a2);
        acc_pair(q0, q1, t0, t1, ef, b1, b2);
    }
}

#define DECLG(k) float4 xa##k, xb##k, ya##k, yb##k; unsigned tw##k, ew##k;
#define LOADG(k) \
    xa##k = *(const float4*)(p0 + (size_t)(k) * 8388608u); \
    xb##k = *(const float4*)(p0 + (size_t)(k) * 8388608u + 1048576u); \
    ya##k = *(const float4*)(p1 + (size_t)(k) * 8388608u); \
    yb##k = *(const float4*)(p1 + (size_t)(k) * 8388608u + 1048576u); \
    tw##k = tb32[w0 + (k) * 131072u]; \
    ew##k = eb32[w0 + (k) * 131072u];
#define COMPG(k) { \
    const unsigned nt = (tw##k >> shift) & 15u; \
    const unsigned ne = (ew##k >> shift) & 15u; \
    proc_group(xa##k, xb##k, ya##k, yb##k, nt, ne, cntv, a1, a2, b1, b2); }

__global__ __launch_bounds__(256)
void loss_stream3(const float* __restrict__ score0,
                  const float* __restrict__ score1,
                  const unsigned int* __restrict__ tb32,
                  const unsigned int* __restrict__ eb32,
                  float* __restrict__ partials) {
    __shared__ float red[4][5];
    const int tid = threadIdx.x;
    const int bid = blockIdx.x;
    const int g   = bid * 256 + tid;                 // 0..1048575

    // P_k = 4g + k*4194304  (k-th batch quartet); in-plane offset same for all k
    const int      b0    = g >> 18;                  // batch of group 0
    const unsigned r     = (4u * (unsigned)g) & 1048575u;
    const unsigned w0    = (unsigned)(g >> 3);       // u32 word of group 0
    const unsigned shift = ((unsigned)g & 7u) * 4u;  // nibble within word

    const float* p0 = score0 + (size_t)b0 * 2097152u + r;
    const float* p1 = score1 + (size_t)b0 * 2097152u + r;

    DECLG(0) DECLG(1) DECLG(2) DECLG(3)

    v2f cntv = {0.f, 0.f}, a1 = {0.f, 0.f}, a2 = {0.f, 0.f};
    v2f b1 = {0.f, 0.f}, b2 = {0.f, 0.f};

    LOADG(0)
    LOADG(1)
    COMPG(0)
    LOADG(2)
    COMPG(1)
    LOADG(3)
    COMPG(2)
    COMPG(3)

    float vals[5] = {cntv.x + cntv.y, a1.x + a1.y, a2.x + a2.y,
                     b1.x + b1.y, b2.x + b2.y};
    const int lane = tid & 63, wv = tid >> 6;
    #pragma unroll
    for (int q = 0; q < 5; ++q) {
        float v = vals[q];
        #pragma unroll
        for (int off = 32; off > 0; off >>= 1) v += __shfl_down(v, off);
        if (lane == 0) red[wv][q] = v;
    }
    __syncthreads();
    if (tid == 0) {
        #pragma unroll
        for (int q = 0; q < 5; ++q)
            partials[q * NB3 + bid] = red[0][q] + red[1][q] + red[2][q] + red[3][q];
    }
}

// ---------------- final reduction (n partial sets) ----------------
__global__ __launch_bounds__(1024)
void finalize_loss(const float* __restrict__ ws, float* __restrict__ out, int n) {
    __shared__ double red[16][5];
    const int tid = threadIdx.x;
    double acc[5] = {0, 0, 0, 0, 0};
    for (int i = tid; i < n; i += 1024) {
        #pragma unroll
        for (int q = 0; q < 5; ++q) acc[q] += (double)ws[q * n + i];
    }
    const int lane = tid & 63, wv = tid >> 6;
    #pragma unroll
    for (int q = 0; q < 5; ++q) {
        double v = acc[q];
        #pragma unroll
        for (int off = 32; off > 0; off >>= 1) v += __shfl_down(v, off);
        if (lane == 0) red[wv][q] = v;
    }
    __syncthreads();
    if (tid == 0) {
        double s[5];
        #pragma unroll
        for (int q = 0; q < 5; ++q) {
            double v = 0;
            for (int w = 0; w < 16; ++w) v += red[w][q];
            s[q] = v;
        }
        const double N = NPIX;
        double alpha = s[0] / N;
        if (alpha > 0.2) alpha = 0.2;
        double loss = (s[1] + alpha * s[2]) + 0.5 * (s[3] + alpha * s[4]);
        out[0] = (float)(-loss / N);
    }
}

// ============================================================================
// Fallback: verified fused baseline (workspace too small for bit planes).
// ============================================================================
__global__ __launch_bounds__(256)
void fused_edge_loss(const float* __restrict__ score0,
                     const float* __restrict__ score1,
                     const int*   __restrict__ target,
                     float*       __restrict__ ws) {
    __shared__ unsigned char  tb[TIH][TB_P];
    __shared__ unsigned short vs[TH][VS_P];
    __shared__ float          red[4][5];

    const int tid   = threadIdx.x;
    const int tileX = blockIdx.x * TW;
    const int tileY = blockIdx.y * TH;
    const int b     = blockIdx.z;
    const int bid   = (blockIdx.z * NBY + blockIdx.y) * NBX + blockIdx.x;

    const int* tgt = target + (size_t)b * (1024 * 1024);

    for (int idx = tid; idx < TIH * TIW; idx += 256) {
        int rr = idx / TIW;
        int cc = idx - rr * TIW;
        int gr = tileY + rr - HALO;
        int gc = tileX + cc - HALO;
        unsigned char v = 0;
        if ((unsigned)gr < 1024u && (unsigned)gc < 1024u)
            v = (unsigned char)tgt[gr * 1024 + gc];
        tb[rr][cc] = v;
    }
    __syncthreads();

    if (tid < TIW) {
        int acc = 0;
        #pragma unroll
        for (int rr = 0; rr < 11; ++rr) acc += tb[rr][tid];
        vs[0][tid] = (unsigned short)acc;
        for (int r = 1; r < TH; ++r) {
            acc += (int)tb[r + 10][tid] - (int)tb[r - 1][tid];
            vs[r][tid] = (unsigned short)acc;
        }
    }
    __syncthreads();

    const float* s0b = score0 + (size_t)b * (2 * 1024 * 1024);
    const float* s1b = score1 + (size_t)b * (2 * 1024 * 1024);
    const int tx = tid & 31;
    const int ty = tid >> 5;

    float cnt = 0.f, a1 = 0.f, a2 = 0.f, b1 = 0.f, b2 = 0.f;

    #pragma unroll
    for (int p = 0; p < 4; ++p) {
        const int r  = ty + p * 8;
        const int gr = tileY + r;
        const int c0 = tx * 4;
        const int gc = tileX + c0;

        int S[4];
        int s = 0;
        #pragma unroll
        for (int k = 0; k < 11; ++k) s += vs[r][c0 + k];
        S[0] = s;
        #pragma unroll
        for (int j = 1; j < 4; ++j) {
            s += (int)vs[r][c0 + 10 + j] - (int)vs[r][c0 + j - 1];
            S[j] = s;
        }

        const size_t base = (size_t)gr * 1024 + gc;
        float4 x0 = *(const float4*)(s0b + base);
        float4 x1 = *(const float4*)(s0b + 1048576 + base);
        float4 y0 = *(const float4*)(s1b + base);
        float4 y1 = *(const float4*)(s1b + 1048576 + base);
        float p0a[4] = {x0.x, x0.y, x0.z, x0.w};
        float p1a[4] = {x1.x, x1.y, x1.z, x1.w};
        float q0a[4] = {y0.x, y0.y, y0.z, y0.w};
        float q1a[4] = {y1.x, y1.y, y1.z, y1.w};

        #pragma unroll
        for (int j = 0; j < 4; ++j) {
            const int t = tb[r + 5][c0 + 5 + j];
            const float e = (S[j] != 121 * t) ? 1.0f : 0.0f;
            cnt += e;
            {
                float p0 = p0a[j], p1 = p1a[j];
                float m   = fmaxf(p0, p1);
                float lse = m + __logf(1.0f + __expf(-fabsf(p0 - p1)));
                float lpt = (t ? p1 : p0) - lse;
                float slp = p0 + p1 - 2.0f * lse;
                a1 += lpt;
                a2 += e * (slp - 1.5f * lpt);
            }
            {
                float q0 = q0a[j], q1 = q1a[j];
                float m   = fmaxf(q0, q1);
                float lse = m + __logf(1.0f + __expf(-fabsf(q0 - q1)));
                float lpt = (t ? q1 : q0) - lse;
                float slp = q0 + q1 - 2.0f * lse;
                b1 += lpt;
                b2 += e * (slp - 1.5f * lpt);
            }
        }
    }

    float vals[5] = {cnt, a1, a2, b1, b2};
    const int lane = tid & 63, wv = tid >> 6;
    #pragma unroll
    for (int q = 0; q < 5; ++q) {
        float v = vals[q];
        #pragma unroll
        for (int off = 32; off > 0; off >>= 1) v += __shfl_down(v, off);
        if (lane == 0) red[wv][q] = v;
    }
    __syncthreads();
    if (tid == 0) {
        #pragma unroll
        for (int q = 0; q < 5; ++q) {
            float v = red[0][q] + red[1][q] + red[2][q] + red[3][q];
            ws[q * NB + bid] = v;
        }
    }
}

extern "C" void kernel_launch(void* const* d_in, const int* in_sizes, int n_in,
                              void* d_out, int out_size, void* d_ws, size_t ws_size,
                              hipStream_t stream) {
    const float* score0 = (const float*)d_in[0];
    const float* score1 = (const float*)d_in[1];
    const int*   target = (const int*)d_in[2];
    float* out = (float*)d_out;
    unsigned char* ws = (unsigned char*)d_ws;

    const size_t need = (size_t)PART_OFF + (size_t)5 * NB3 * 4;  // 4 MB + 80 KB
    if (ws_size >= need) {
        unsigned int* tb = (unsigned int*)(ws + TBITS_OFF);
        u64*          eb = (u64*)(ws + EBITS_OFF);
        float*  partials = (float*)(ws + PART_OFF);
        pack_bits32<<<2048, 256, 0, stream>>>(target, tb);
        edge_bits<<<1024, 256, 0, stream>>>((const u64*)tb, eb);
        loss_stream3<<<NB3, 256, 0, stream>>>(score0, score1,
                                              (const unsigned int*)tb,
                                              (const unsigned int*)eb, partials);
        finalize_loss<<<1, 1024, 0, stream>>>(partials, out, NB3);
    } else {
        float* partials = (float*)ws;
        dim3 grid(NBX, NBY, NBZ);
        fused_edge_loss<<<grid, 256, 0, stream>>>(score0, score1, target, partials);
        finalize_loss<<<1, 1024, 0, stream>>>(partials, out, NB);
    }
}

// Round 5
// 326.761 us; speedup vs baseline: 1.0611x; 1.0055x over previous
//
#include <hip/hip_runtime.h>

typedef float v2f __attribute__((ext_vector_type(2)));
typedef unsigned long long u64;

#define NPIX 16777216.0

// ---- workspace layout (split path) ----
#define TBITS_OFF 0u
#define EBITS_OFF (2u*1024u*1024u)          // t-bits: 2 MB
#define PART_OFF  (4u*1024u*1024u)          // e-bits: 2 MB
#define NB4       4096                      // loss_stream4 grid
// partials: 5*NB4*4 = 80 KB at PART_OFF

// ---- fallback (fused) geometry ----
#define TW   128
#define TH   32
#define HALO 5
#define TIW  (TW + 2*HALO)
#define TIH  (TH + 2*HALO)
#define TB_P 144
#define VS_P 142
#define NBX  8
#define NBY  32
#define NBZ  16
#define NB   (NBX*NBY*NBZ)

// ============================================================================
// K0: pack target (int32 0/1) into bit plane. 32 px/thread: 8x int4 loads,
// local bit build, one coalesced u32 store. 2048 blocks x 256 threads.
// ============================================================================
__device__ __forceinline__ unsigned nib(int4 r) {
    return (unsigned)((r.x & 1) | ((r.y & 1) << 1) | ((r.z & 1) << 2) | ((r.w & 1) << 3));
}

__global__ __launch_bounds__(256)
void pack_bits32(const int* __restrict__ target, unsigned int* __restrict__ tb32) {
    const int G = blockIdx.x * 256 + threadIdx.x;        // 0..524287
    const int4* p = (const int4*)target + (size_t)G * 8; // 32 consecutive int32
    const int4 r0 = p[0], r1 = p[1], r2 = p[2], r3 = p[3];
    const int4 r4 = p[4], r5 = p[5], r6 = p[6], r7 = p[7];
    unsigned m = nib(r0);
    m |= nib(r1) << 4;
    m |= nib(r2) << 8;
    m |= nib(r3) << 12;
    m |= nib(r4) << 16;
    m |= nib(r5) << 20;
    m |= nib(r6) << 24;
    m |= nib(r7) << 28;
    tb32[G] = m;   // u32 word G covers pixels [32G, 32G+32), little-endian bits
}

// ============================================================================
// K1: edge bits. edge=1 iff 11x11 window (zero-padded) is non-constant,
// i.e. winOR != winAND (== Laplacian != 0 for 0/1 input). Separable:
// vertical OR/AND over 11 rows, then horizontal 11-window via funnel shifts.
// One thread per (batch,row,word): 262144 threads.
// ============================================================================
__device__ __forceinline__ u64 hor11_or(u64 L, u64 M, u64 R) {
    u64 o = M;
    o |= (M >> 1) | (R << 63);
    o |= (M >> 2) | (R << 62);
    o |= (M >> 3) | (R << 61);
    o |= (M >> 4) | (R << 60);
    o |= (M >> 5) | (R << 59);
    o |= (M << 1) | (L >> 63);
    o |= (M << 2) | (L >> 62);
    o |= (M << 3) | (L >> 61);
    o |= (M << 4) | (L >> 60);
    o |= (M << 5) | (L >> 59);
    return o;
}
__device__ __forceinline__ u64 hor11_and(u64 L, u64 M, u64 R) {
    u64 a = M;
    a &= (M >> 1) | (R << 63);
    a &= (M >> 2) | (R << 62);
    a &= (M >> 3) | (R << 61);
    a &= (M >> 4) | (R << 60);
    a &= (M >> 5) | (R << 59);
    a &= (M << 1) | (L >> 63);
    a &= (M << 2) | (L >> 62);
    a &= (M << 3) | (L >> 61);
    a &= (M << 4) | (L >> 60);
    a &= (M << 5) | (L >> 59);
    return a;
}

__global__ __launch_bounds__(256)
void edge_bits(const u64* __restrict__ tbits, u64* __restrict__ ebits) {
    const int idx = blockIdx.x * 256 + threadIdx.x;   // 0..262143
    const int wi  = idx & 15;
    const int row = (idx >> 4) & 1023;
    const int b   = idx >> 14;
    const u64* plane = tbits + (size_t)b * 16384;

    u64 oL = 0, oM = 0, oR = 0;
    u64 aL = ~0ull, aM = ~0ull, aR = ~0ull;
    #pragma unroll
    for (int dr = -5; dr <= 5; ++dr) {
        const int r = row + dr;
        u64 L = 0, M = 0, R = 0;
        if ((unsigned)r < 1024u) {
            const u64* rp = plane + (size_t)r * 16;
            L = (wi > 0)  ? rp[wi - 1] : 0ull;
            M = rp[wi];
            R = (wi < 15) ? rp[wi + 1] : 0ull;
        }
        oL |= L; oM |= M; oR |= R;
        aL &= L; aM &= M; aR &= R;
    }
    const u64 O = hor11_or(oL, oM, oR);
    const u64 A = hor11_and(aL, aM, aR);
    ebits[idx] = O ^ A;
}

// ============================================================================
// K2: streaming loss, CONTIGUOUS sweep. 4096 blocks x 256 thr; each thread
// owns 16 CONSECUTIVE pixels of ONE batch: 4 consecutive float4 per plane
// (4 streams/thread, immediate-offset folded), one 16-bit mask field.
// Consecutive blocks sweep the score arrays linearly -> few chip-wide DRAM
// stream fronts (row-buffer friendly), vs 12-16 scattered streams before.
// ============================================================================
__device__ __forceinline__ void acc_pair(v2f p0, v2f p1, unsigned t0, unsigned t1,
                                         v2f ef, v2f& s1, v2f& s2) {
    v2f d = p0 - p1;
    v2f sp;
    sp.x = __logf(1.0f + __expf(-fabsf(d.x)));
    sp.y = __logf(1.0f + __expf(-fabsf(d.y)));
    v2f m;
    m.x = fmaxf(p0.x, p1.x);
    m.y = fmaxf(p0.y, p1.y);
    v2f lse = m + sp;
    v2f pt;                          // exact select (no fma reassociation)
    pt.x = t0 ? p1.x : p0.x;
    pt.y = t1 ? p1.y : p0.y;
    v2f lpt = pt - lse;
    v2f slp = (p0 + p1) - 2.0f * lse;
    s1 += lpt;
    s2 += ef * (slp - 1.5f * lpt);
}

__device__ __forceinline__ void proc_group(float4 x0, float4 x1, float4 y0, float4 y1,
                                           unsigned nt, unsigned ne,
                                           v2f& cntv, v2f& a1, v2f& a2, v2f& b1, v2f& b2) {
    #pragma unroll
    for (int h = 0; h < 2; ++h) {
        const unsigned t0 = (nt >> (2 * h)) & 1u;
        const unsigned t1 = (nt >> (2 * h + 1)) & 1u;
        const unsigned e0 = (ne >> (2 * h)) & 1u;
        const unsigned e1 = (ne >> (2 * h + 1)) & 1u;
        v2f ef; ef.x = (float)e0; ef.y = (float)e1;
        cntv += ef;
        v2f p0, p1, q0, q1;
        p0.x = h ? x0.z : x0.x;  p0.y = h ? x0.w : x0.y;
        p1.x = h ? x1.z : x1.x;  p1.y = h ? x1.w : x1.y;
        q0.x = h ? y0.z : y0.x;  q0.y = h ? y0.w : y0.y;
        q1.x = h ? y1.z : y1.x;  q1.y = h ? y1.w : y1.y;
        acc_pair(p0, p1, t0, t1, ef, a1, a2);
        acc_pair(q0, q1, t0, t1, ef, b1, b2);
    }
}

__global__ __launch_bounds__(256)
void loss_stream4(const float* __restrict__ score0,
                  const float* __restrict__ score1,
                  const unsigned int* __restrict__ tb32,
                  const unsigned int* __restrict__ eb32,
                  float* __restrict__ partials) {
    __shared__ float red[4][5];
    const int tid = threadIdx.x;
    const int bid = blockIdx.x;
    const int g   = bid * 256 + tid;                 // 0..1048575

    // 16 consecutive pixels: P = 16g .. 16g+15, all in batch b = g>>16
    const int      b     = g >> 16;
    const unsigned r     = (16u * (unsigned)g) & 1048575u;
    const unsigned w     = (unsigned)(g >> 1);       // u32 bit word (32 px)
    const unsigned shift = ((unsigned)g & 1u) * 16u; // which 16-bit half

    const float* s0 = score0 + (size_t)b * 2097152u + r;   // score0 class0
    const float* s1 = score1 + (size_t)b * 2097152u + r;   // score1 class0

    // ---- load burst: 16x float4 (4 consecutive per plane) + 2x u32 ----
    const float4 x00 = *(const float4*)(s0 + 0);
    const float4 x01 = *(const float4*)(s0 + 4);
    const float4 x02 = *(const float4*)(s0 + 8);
    const float4 x03 = *(const float4*)(s0 + 12);
    const float4 x10 = *(const float4*)(s0 + 1048576u + 0);
    const float4 x11 = *(const float4*)(s0 + 1048576u + 4);
    const float4 x12 = *(const float4*)(s0 + 1048576u + 8);
    const float4 x13 = *(const float4*)(s0 + 1048576u + 12);
    const float4 y00 = *(const float4*)(s1 + 0);
    const float4 y01 = *(const float4*)(s1 + 4);
    const float4 y02 = *(const float4*)(s1 + 8);
    const float4 y03 = *(const float4*)(s1 + 12);
    const float4 y10 = *(const float4*)(s1 + 1048576u + 0);
    const float4 y11 = *(const float4*)(s1 + 1048576u + 4);
    const float4 y12 = *(const float4*)(s1 + 1048576u + 8);
    const float4 y13 = *(const float4*)(s1 + 1048576u + 12);
    const unsigned nt16 = (tb32[w] >> shift) & 0xffffu;
    const unsigned ne16 = (eb32[w] >> shift) & 0xffffu;

    v2f cntv = {0.f, 0.f}, a1 = {0.f, 0.f}, a2 = {0.f, 0.f};
    v2f b1 = {0.f, 0.f}, b2 = {0.f, 0.f};

    proc_group(x00, x10, y00, y10, (nt16 >>  0) & 15u, (ne16 >>  0) & 15u, cntv, a1, a2, b1, b2);
    proc_group(x01, x11, y01, y11, (nt16 >>  4) & 15u, (ne16 >>  4) & 15u, cntv, a1, a2, b1, b2);
    proc_group(x02, x12, y02, y12, (nt16 >>  8) & 15u, (ne16 >>  8) & 15u, cntv, a1, a2, b1, b2);
    proc_group(x03, x13, y03, y13, (nt16 >> 12) & 15u, (ne16 >> 12) & 15u, cntv, a1, a2, b1, b2);

    float vals[5] = {cntv.x + cntv.y, a1.x + a1.y, a2.x + a2.y,
                     b1.x + b1.y, b2.x + b2.y};
    const int lane = tid & 63, wv = tid >> 6;
    #pragma unroll
    for (int q = 0; q < 5; ++q) {
        float v = vals[q];
        #pragma unroll
        for (int off = 32; off > 0; off >>= 1) v += __shfl_down(v, off);
        if (lane == 0) red[wv][q] = v;
    }
    __syncthreads();
    if (tid == 0) {
        #pragma unroll
        for (int q = 0; q < 5; ++q)
            partials[q * NB4 + bid] = red[0][q] + red[1][q] + red[2][q] + red[3][q];
    }
}

// ---------------- final reduction (n partial sets) ----------------
__global__ __launch_bounds__(1024)
void finalize_loss(const float* __restrict__ ws, float* __restrict__ out, int n) {
    __shared__ double red[16][5];
    const int tid = threadIdx.x;
    double acc[5] = {0, 0, 0, 0, 0};
    for (int i = tid; i < n; i += 1024) {
        #pragma unroll
        for (int q = 0; q < 5; ++q) acc[q] += (double)ws[q * n + i];
    }
    const int lane = tid & 63, wv = tid >> 6;
    #pragma unroll
    for (int q = 0; q < 5; ++q) {
        double v = acc[q];
        #pragma unroll
        for (int off = 32; off > 0; off >>= 1) v += __shfl_down(v, off);
        if (lane == 0) red[wv][q] = v;
    }
    __syncthreads();
    if (tid == 0) {
        double s[5];
        #pragma unroll
        for (int q = 0; q < 5; ++q) {
            double v = 0;
            for (int w = 0; w < 16; ++w) v += red[w][q];
            s[q] = v;
        }
        const double N = NPIX;
        double alpha = s[0] / N;
        if (alpha > 0.2) alpha = 0.2;
        double loss = (s[1] + alpha * s[2]) + 0.5 * (s[3] + alpha * s[4]);
        out[0] = (float)(-loss / N);
    }
}

// ============================================================================
// Fallback: verified fused baseline (workspace too small for bit planes).
// ============================================================================
__global__ __launch_bounds__(256)
void fused_edge_loss(const float* __restrict__ score0,
                     const float* __restrict__ score1,
                     const int*   __restrict__ target,
                     float*       __restrict__ ws) {
    __shared__ unsigned char  tb[TIH][TB_P];
    __shared__ unsigned short vs[TH][VS_P];
    __shared__ float          red[4][5];

    const int tid   = threadIdx.x;
    const int tileX = blockIdx.x * TW;
    const int tileY = blockIdx.y * TH;
    const int b     = blockIdx.z;
    const int bid   = (blockIdx.z * NBY + blockIdx.y) * NBX + blockIdx.x;

    const int* tgt = target + (size_t)b * (1024 * 1024);

    for (int idx = tid; idx < TIH * TIW; idx += 256) {
        int rr = idx / TIW;
        int cc = idx - rr * TIW;
        int gr = tileY + rr - HALO;
        int gc = tileX + cc - HALO;
        unsigned char v = 0;
        if ((unsigned)gr < 1024u && (unsigned)gc < 1024u)
            v = (unsigned char)tgt[gr * 1024 + gc];
        tb[rr][cc] = v;
    }
    __syncthreads();

    if (tid < TIW) {
        int acc = 0;
        #pragma unroll
        for (int rr = 0; rr < 11; ++rr) acc += tb[rr][tid];
        vs[0][tid] = (unsigned short)acc;
        for (int r = 1; r < TH; ++r) {
            acc += (int)tb[r + 10][tid] - (int)tb[r - 1][tid];
            vs[r][tid] = (unsigned short)acc;
        }
    }
    __syncthreads();

    const float* s0b = score0 + (size_t)b * (2 * 1024 * 1024);
    const float* s1b = score1 + (size_t)b * (2 * 1024 * 1024);
    const int tx = tid & 31;
    const int ty = tid >> 5;

    float cnt = 0.f, a1 = 0.f, a2 = 0.f, b1 = 0.f, b2 = 0.f;

    #pragma unroll
    for (int p = 0; p < 4; ++p) {
        const int r  = ty + p * 8;
        const int gr = tileY + r;
        const int c0 = tx * 4;
        const int gc = tileX + c0;

        int S[4];
        int s = 0;
        #pragma unroll
        for (int k = 0; k < 11; ++k) s += vs[r][c0 + k];
        S[0] = s;
        #pragma unroll
        for (int j = 1; j < 4; ++j) {
            s += (int)vs[r][c0 + 10 + j] - (int)vs[r][c0 + j - 1];
            S[j] = s;
        }

        const size_t base = (size_t)gr * 1024 + gc;
        float4 x0 = *(const float4*)(s0b + base);
        float4 x1 = *(const float4*)(s0b + 1048576 + base);
        float4 y0 = *(const float4*)(s1b + base);
        float4 y1 = *(const float4*)(s1b + 1048576 + base);
        float p0a[4] = {x0.x, x0.y, x0.z, x0.w};
        float p1a[4] = {x1.x, x1.y, x1.z, x1.w};
        float q0a[4] = {y0.x, y0.y, y0.z, y0.w};
        float q1a[4] = {y1.x, y1.y, y1.z, y1.w};

        #pragma unroll
        for (int j = 0; j < 4; ++j) {
            const int t = tb[r + 5][c0 + 5 + j];
            const float e = (S[j] != 121 * t) ? 1.0f : 0.0f;
            cnt += e;
            {
                float p0 = p0a[j], p1 = p1a[j];
                float m   = fmaxf(p0, p1);
                float lse = m + __logf(1.0f + __expf(-fabsf(p0 - p1)));
                float lpt = (t ? p1 : p0) - lse;
                float slp = p0 + p1 - 2.0f * lse;
                a1 += lpt;
                a2 += e * (slp - 1.5f * lpt);
            }
            {
                float q0 = q0a[j], q1 = q1a[j];
                float m   = fmaxf(q0, q1);
                float lse = m + __logf(1.0f + __expf(-fabsf(q0 - q1)));
                float lpt = (t ? q1 : q0) - lse;
                float slp = q0 + q1 - 2.0f * lse;
                b1 += lpt;
                b2 += e * (slp - 1.5f * lpt);
            }
        }
    }

    float vals[5] = {cnt, a1, a2, b1, b2};
    const int lane = tid & 63, wv = tid >> 6;
    #pragma unroll
    for (int q = 0; q < 5; ++q) {
        float v = vals[q];
        #pragma unroll
        for (int off = 32; off > 0; off >>= 1) v += __shfl_down(v, off);
        if (lane == 0) red[wv][q] = v;
    }
    __syncthreads();
    if (tid == 0) {
        #pragma unroll
        for (int q = 0; q < 5; ++q) {
            float v = red[0][q] + red[1][q] + red[2][q] + red[3][q];
            ws[q * NB + bid] = v;
        }
    }
}

extern "C" void kernel_launch(void* const* d_in, const int* in_sizes, int n_in,
                              void* d_out, int out_size, void* d_ws, size_t ws_size,
                              hipStream_t stream) {
    const float* score0 = (const float*)d_in[0];
    const float* score1 = (const float*)d_in[1];
    const int*   target = (const int*)d_in[2];
    float* out = (float*)d_out;
    unsigned char* ws = (unsigned char*)d_ws;

    const size_t need = (size_t)PART_OFF + (size_t)5 * NB4 * 4;  // 4 MB + 80 KB
    if (ws_size >= need) {
        unsigned int* tb = (unsigned int*)(ws + TBITS_OFF);
        u64*          eb = (u64*)(ws + EBITS_OFF);
        float*  partials = (float*)(ws + PART_OFF);
        pack_bits32<<<2048, 256, 0, stream>>>(target, tb);
        edge_bits<<<1024, 256, 0, stream>>>((const u64*)tb, eb);
        loss_stream4<<<NB4, 256, 0, stream>>>(score0, score1,
                                              (const unsigned int*)tb,
                                              (const unsigned int*)eb, partials);
        finalize_loss<<<1, 1024, 0, stream>>>(partials, out, NB4);
    } else {
        float* partials = (float*)ws;
        dim3 grid(NBX, NBY, NBZ);
        fused_edge_loss<<<grid, 256, 0, stream>>>(score0, score1, target, partials);
        finalize_loss<<<1, 1024, 0, stream>>>(partials, out, NB);
    }
}

// Round 6
// 324.023 us; speedup vs baseline: 1.0701x; 1.0084x over previous
//
#include <hip/hip_runtime.h>

typedef float v2f __attribute__((ext_vector_type(2)));
typedef unsigned long long u64;

#define NPIX 16777216.0

// ---- workspace layout (split path) ----
#define TBITS_OFF 0u
#define EBITS_OFF (2u*1024u*1024u)          // t-bits: 2 MB
#define PART_OFF  (4u*1024u*1024u)          // e-bits: 2 MB
#define NB5       2048                      // loss_stream5 grid
// partials: 5*NB5*4 = 40 KB at PART_OFF

// ---- fallback (fused) geometry ----
#define TW   128
#define TH   32
#define HALO 5
#define TIW  (TW + 2*HALO)
#define TIH  (TH + 2*HALO)
#define TB_P 144
#define VS_P 142
#define NBX  8
#define NBY  32
#define NBZ  16
#define NB   (NBX*NBY*NBZ)

// ============================================================================
// K0: pack target (int32 0/1) into bit plane. 32 px/thread: 8x int4 loads,
// local bit build, one coalesced u32 store. 2048 blocks x 256 threads.
// ============================================================================
__device__ __forceinline__ unsigned nib(int4 r) {
    return (unsigned)((r.x & 1) | ((r.y & 1) << 1) | ((r.z & 1) << 2) | ((r.w & 1) << 3));
}

__global__ __launch_bounds__(256)
void pack_bits32(const int* __restrict__ target, unsigned int* __restrict__ tb32) {
    const int G = blockIdx.x * 256 + threadIdx.x;        // 0..524287
    const int4* p = (const int4*)target + (size_t)G * 8; // 32 consecutive int32
    const int4 r0 = p[0], r1 = p[1], r2 = p[2], r3 = p[3];
    const int4 r4 = p[4], r5 = p[5], r6 = p[6], r7 = p[7];
    unsigned m = nib(r0);
    m |= nib(r1) << 4;
    m |= nib(r2) << 8;
    m |= nib(r3) << 12;
    m |= nib(r4) << 16;
    m |= nib(r5) << 20;
    m |= nib(r6) << 24;
    m |= nib(r7) << 28;
    tb32[G] = m;   // u32 word G covers pixels [32G, 32G+32), little-endian bits
}

// ============================================================================
// K1: edge bits. edge=1 iff 11x11 window (zero-padded) is non-constant,
// i.e. winOR != winAND (== Laplacian != 0 for 0/1 input). Separable:
// vertical OR/AND over 11 rows, then horizontal 11-window via funnel shifts.
// One thread per (batch,row,word): 262144 threads.
// ============================================================================
__device__ __forceinline__ u64 hor11_or(u64 L, u64 M, u64 R) {
    u64 o = M;
    o |= (M >> 1) | (R << 63);
    o |= (M >> 2) | (R << 62);
    o |= (M >> 3) | (R << 61);
    o |= (M >> 4) | (R << 60);
    o |= (M >> 5) | (R << 59);
    o |= (M << 1) | (L >> 63);
    o |= (M << 2) | (L >> 62);
    o |= (M << 3) | (L >> 61);
    o |= (M << 4) | (L >> 60);
    o |= (M << 5) | (L >> 59);
    return o;
}
__device__ __forceinline__ u64 hor11_and(u64 L, u64 M, u64 R) {
    u64 a = M;
    a &= (M >> 1) | (R << 63);
    a &= (M >> 2) | (R << 62);
    a &= (M >> 3) | (R << 61);
    a &= (M >> 4) | (R << 60);
    a &= (M >> 5) | (R << 59);
    a &= (M << 1) | (L >> 63);
    a &= (M << 2) | (L >> 62);
    a &= (M << 3) | (L >> 61);
    a &= (M << 4) | (L >> 60);
    a &= (M << 5) | (L >> 59);
    return a;
}

__global__ __launch_bounds__(256)
void edge_bits(const u64* __restrict__ tbits, u64* __restrict__ ebits) {
    const int idx = blockIdx.x * 256 + threadIdx.x;   // 0..262143
    const int wi  = idx & 15;
    const int row = (idx >> 4) & 1023;
    const int b   = idx >> 14;
    const u64* plane = tbits + (size_t)b * 16384;

    u64 oL = 0, oM = 0, oR = 0;
    u64 aL = ~0ull, aM = ~0ull, aR = ~0ull;
    #pragma unroll
    for (int dr = -5; dr <= 5; ++dr) {
        const int r = row + dr;
        u64 L = 0, M = 0, R = 0;
        if ((unsigned)r < 1024u) {
            const u64* rp = plane + (size_t)r * 16;
            L = (wi > 0)  ? rp[wi - 1] : 0ull;
            M = rp[wi];
            R = (wi < 15) ? rp[wi + 1] : 0ull;
        }
        oL |= L; oM |= M; oR |= R;
        aL &= L; aM &= M; aR &= R;
    }
    const u64 O = hor11_or(oL, oM, oR);
    const u64 A = hor11_and(aL, aM, aR);
    ebits[idx] = O ^ A;
}

// ============================================================================
// K2: streaming loss, SUSTAINED depth-2 pipeline. 2048 blocks x 256 thr;
// each thread: 8 iterations x 4 px. Three named register buffers rotate so
// 1-2 iterations of loads (4-8 dwordx4 + dwords) are outstanding during
// EVERY compute phase for the whole kernel (copy-kernel-like MLP profile),
// vs the previous one-shot bursts that drained then computed dry.
// Block sweeps 32 KB contiguous per plane; all loads lane-coalesced.
// ============================================================================
__device__ __forceinline__ void acc_pair(v2f p0, v2f p1, unsigned t0, unsigned t1,
                                         v2f ef, v2f& s1, v2f& s2) {
    v2f d = p0 - p1;
    v2f sp;
    sp.x = __logf(1.0f + __expf(-fabsf(d.x)));
    sp.y = __logf(1.0f + __expf(-fabsf(d.y)));
    v2f m;
    m.x = fmaxf(p0.x, p1.x);
    m.y = fmaxf(p0.y, p1.y);
    v2f lse = m + sp;
    v2f pt;                          // exact select (no fma reassociation)
    pt.x = t0 ? p1.x : p0.x;
    pt.y = t1 ? p1.y : p0.y;
    v2f lpt = pt - lse;
    v2f slp = (p0 + p1) - 2.0f * lse;
    s1 += lpt;
    s2 += ef * (slp - 1.5f * lpt);
}

__device__ __forceinline__ void proc_group(float4 x0, float4 x1, float4 y0, float4 y1,
                                           unsigned nt, unsigned ne,
                                           v2f& cntv, v2f& a1, v2f& a2, v2f& b1, v2f& b2) {
    #pragma unroll
    for (int h = 0; h < 2; ++h) {
        const unsigned t0 = (nt >> (2 * h)) & 1u;
        const unsigned t1 = (nt >> (2 * h + 1)) & 1u;
        const unsigned e0 = (ne >> (2 * h)) & 1u;
        const unsigned e1 = (ne >> (2 * h + 1)) & 1u;
        v2f ef; ef.x = (float)e0; ef.y = (float)e1;
        cntv += ef;
        v2f p0, p1, q0, q1;
        p0.x = h ? x0.z : x0.x;  p0.y = h ? x0.w : x0.y;
        p1.x = h ? x1.z : x1.x;  p1.y = h ? x1.w : x1.y;
        q0.x = h ? y0.z : y0.x;  q0.y = h ? y0.w : y0.y;
        q1.x = h ? y1.z : y1.x;  q1.y = h ? y1.w : y1.y;
        acc_pair(p0, p1, t0, t1, ef, a1, a2);
        acc_pair(q0, q1, t0, t1, ef, b1, b2);
    }
}

// named buffers: B in {A,B,C}; iteration k in 0..7 (px offset k*1024 floats)
#define DECLB(B) float4 x0##B, x1##B, y0##B, y1##B; unsigned tw##B, ew##B;
#define LOADI(B, k) \
    x0##B = *(const float4*)(p0 + (k) * 1024u); \
    x1##B = *(const float4*)(p0 + 1048576u + (k) * 1024u); \
    y0##B = *(const float4*)(p1 + (k) * 1024u); \
    y1##B = *(const float4*)(p1 + 1048576u + (k) * 1024u); \
    tw##B = tb32[wbase + (k) * 32u]; \
    ew##B = eb32[wbase + (k) * 32u];
#define COMPI(B) { \
    const unsigned nt = (tw##B >> shift) & 15u; \
    const unsigned ne = (ew##B >> shift) & 15u; \
    proc_group(x0##B, x1##B, y0##B, y1##B, nt, ne, cntv, a1, a2, b1, b2); }

__global__ __launch_bounds__(256)
void loss_stream5(const float* __restrict__ score0,
                  const float* __restrict__ score1,
                  const unsigned int* __restrict__ tb32,
                  const unsigned int* __restrict__ eb32,
                  float* __restrict__ partials) {
    __shared__ float red[4][5];
    const int tid = threadIdx.x;
    const int bid = blockIdx.x;                      // 0..2047

    // block owns 8192 consecutive px of one batch: base = bid*8192
    const int      bb    = bid >> 7;                 // batch (8192*128 = 1M)
    const unsigned r0    = ((unsigned)bid & 127u) * 8192u + 4u * (unsigned)tid;
    const unsigned wbase = ((unsigned)bid * 8192u + 4u * (unsigned)tid) >> 5;
    const unsigned shift = (4u * (unsigned)tid) & 31u;

    const float* p0 = score0 + (size_t)bb * 2097152u + r0;
    const float* p1 = score1 + (size_t)bb * 2097152u + r0;

    DECLB(A) DECLB(B) DECLB(C)

    v2f cntv = {0.f, 0.f}, a1 = {0.f, 0.f}, a2 = {0.f, 0.f};
    v2f b1 = {0.f, 0.f}, b2 = {0.f, 0.f};

    LOADI(A, 0) LOADI(B, 1)
    COMPI(A)    LOADI(C, 2)
    COMPI(B)    LOADI(A, 3)
    COMPI(C)    LOADI(B, 4)
    COMPI(A)    LOADI(C, 5)
    COMPI(B)    LOADI(A, 6)
    COMPI(C)    LOADI(B, 7)
    COMPI(A)
    COMPI(B)

    float vals[5] = {cntv.x + cntv.y, a1.x + a1.y, a2.x + a2.y,
                     b1.x + b1.y, b2.x + b2.y};
    const int lane = tid & 63, wv = tid >> 6;
    #pragma unroll
    for (int q = 0; q < 5; ++q) {
        float v = vals[q];
        #pragma unroll
        for (int off = 32; off > 0; off >>= 1) v += __shfl_down(v, off);
        if (lane == 0) red[wv][q] = v;
    }
    __syncthreads();
    if (tid == 0) {
        #pragma unroll
        for (int q = 0; q < 5; ++q)
            partials[q * NB5 + bid] = red[0][q] + red[1][q] + red[2][q] + red[3][q];
    }
}

// ---------------- final reduction (n partial sets) ----------------
__global__ __launch_bounds__(1024)
void finalize_loss(const float* __restrict__ ws, float* __restrict__ out, int n) {
    __shared__ double red[16][5];
    const int tid = threadIdx.x;
    double acc[5] = {0, 0, 0, 0, 0};
    for (int i = tid; i < n; i += 1024) {
        #pragma unroll
        for (int q = 0; q < 5; ++q) acc[q] += (double)ws[q * n + i];
    }
    const int lane = tid & 63, wv = tid >> 6;
    #pragma unroll
    for (int q = 0; q < 5; ++q) {
        double v = acc[q];
        #pragma unroll
        for (int off = 32; off > 0; off >>= 1) v += __shfl_down(v, off);
        if (lane == 0) red[wv][q] = v;
    }
    __syncthreads();
    if (tid == 0) {
        double s[5];
        #pragma unroll
        for (int q = 0; q < 5; ++q) {
            double v = 0;
            for (int w = 0; w < 16; ++w) v += red[w][q];
            s[q] = v;
        }
        const double N = NPIX;
        double alpha = s[0] / N;
        if (alpha > 0.2) alpha = 0.2;
        double loss = (s[1] + alpha * s[2]) + 0.5 * (s[3] + alpha * s[4]);
        out[0] = (float)(-loss / N);
    }
}

// ============================================================================
// Fallback: verified fused baseline (workspace too small for bit planes).
// ============================================================================
__global__ __launch_bounds__(256)
void fused_edge_loss(const float* __restrict__ score0,
                     const float* __restrict__ score1,
                     const int*   __restrict__ target,
                     float*       __restrict__ ws) {
    __shared__ unsigned char  tb[TIH][TB_P];
    __shared__ unsigned short vs[TH][VS_P];
    __shared__ float          red[4][5];

    const int tid   = threadIdx.x;
    const int tileX = blockIdx.x * TW;
    const int tileY = blockIdx.y * TH;
    const int b     = blockIdx.z;
    const int bid   = (blockIdx.z * NBY + blockIdx.y) * NBX + blockIdx.x;

    const int* tgt = target + (size_t)b * (1024 * 1024);

    for (int idx = tid; idx < TIH * TIW; idx += 256) {
        int rr = idx / TIW;
        int cc = idx - rr * TIW;
        int gr = tileY + rr - HALO;
        int gc = tileX + cc - HALO;
        unsigned char v = 0;
        if ((unsigned)gr < 1024u && (unsigned)gc < 1024u)
            v = (unsigned char)tgt[gr * 1024 + gc];
        tb[rr][cc] = v;
    }
    __syncthreads();

    if (tid < TIW) {
        int acc = 0;
        #pragma unroll
        for (int rr = 0; rr < 11; ++rr) acc += tb[rr][tid];
        vs[0][tid] = (unsigned short)acc;
        for (int r = 1; r < TH; ++r) {
            acc += (int)tb[r + 10][tid] - (int)tb[r - 1][tid];
            vs[r][tid] = (unsigned short)acc;
        }
    }
    __syncthreads();

    const float* s0b = score0 + (size_t)b * (2 * 1024 * 1024);
    const float* s1b = score1 + (size_t)b * (2 * 1024 * 1024);
    const int tx = tid & 31;
    const int ty = tid >> 5;

    float cnt = 0.f, a1 = 0.f, a2 = 0.f, b1 = 0.f, b2 = 0.f;

    #pragma unroll
    for (int p = 0; p < 4; ++p) {
        const int r  = ty + p * 8;
        const int gr = tileY + r;
        const int c0 = tx * 4;
        const int gc = tileX + c0;

        int S[4];
        int s = 0;
        #pragma unroll
        for (int k = 0; k < 11; ++k) s += vs[r][c0 + k];
        S[0] = s;
        #pragma unroll
        for (int j = 1; j < 4; ++j) {
            s += (int)vs[r][c0 + 10 + j] - (int)vs[r][c0 + j - 1];
            S[j] = s;
        }

        const size_t base = (size_t)gr * 1024 + gc;
        float4 x0 = *(const float4*)(s0b + base);
        float4 x1 = *(const float4*)(s0b + 1048576 + base);
        float4 y0 = *(const float4*)(s1b + base);
        float4 y1 = *(const float4*)(s1b + 1048576 + base);
        float p0a[4] = {x0.x, x0.y, x0.z, x0.w};
        float p1a[4] = {x1.x, x1.y, x1.z, x1.w};
        float q0a[4] = {y0.x, y0.y, y0.z, y0.w};
        float q1a[4] = {y1.x, y1.y, y1.z, y1.w};

        #pragma unroll
        for (int j = 0; j < 4; ++j) {
            const int t = tb[r + 5][c0 + 5 + j];
            const float e = (S[j] != 121 * t) ? 1.0f : 0.0f;
            cnt += e;
            {
                float p0 = p0a[j], p1 = p1a[j];
                float m   = fmaxf(p0, p1);
                float lse = m + __logf(1.0f + __expf(-fabsf(p0 - p1)));
                float lpt = (t ? p1 : p0) - lse;
                float slp = p0 + p1 - 2.0f * lse;
                a1 += lpt;
                a2 += e * (slp - 1.5f * lpt);
            }
            {
                float q0 = q0a[j], q1 = q1a[j];
                float m   = fmaxf(q0, q1);
                float lse = m + __logf(1.0f + __expf(-fabsf(q0 - q1)));
                float lpt = (t ? q1 : q0) - lse;
                float slp = q0 + q1 - 2.0f * lse;
                b1 += lpt;
                b2 += e * (slp - 1.5f * lpt);
            }
        }
    }

    float vals[5] = {cnt, a1, a2, b1, b2};
    const int lane = tid & 63, wv = tid >> 6;
    #pragma unroll
    for (int q = 0; q < 5; ++q) {
        float v = vals[q];
        #pragma unroll
        for (int off = 32; off > 0; off >>= 1) v += __shfl_down(v, off);
        if (lane == 0) red[wv][q] = v;
    }
    __syncthreads();
    if (tid == 0) {
        #pragma unroll
        for (int q = 0; q < 5; ++q) {
            float v = red[0][q] + red[1][q] + red[2][q] + red[3][q];
            ws[q * NB + bid] = v;
        }
    }
}

extern "C" void kernel_launch(void* const* d_in, const int* in_sizes, int n_in,
                              void* d_out, int out_size, void* d_ws, size_t ws_size,
                              hipStream_t stream) {
    const float* score0 = (const float*)d_in[0];
    const float* score1 = (const float*)d_in[1];
    const int*   target = (const int*)d_in[2];
    float* out = (float*)d_out;
    unsigned char* ws = (unsigned char*)d_ws;

    const size_t need = (size_t)PART_OFF + (size_t)5 * NB5 * 4;  // 4 MB + 40 KB
    if (ws_size >= need) {
        unsigned int* tb = (unsigned int*)(ws + TBITS_OFF);
        u64*          eb = (u64*)(ws + EBITS_OFF);
        float*  partials = (float*)(ws + PART_OFF);
        pack_bits32<<<2048, 256, 0, stream>>>(target, tb);
        edge_bits<<<1024, 256, 0, stream>>>((const u64*)tb, eb);
        loss_stream5<<<NB5, 256, 0, stream>>>(score0, score1,
                                              (const unsigned int*)tb,
                                              (const unsigned int*)eb, partials);
        finalize_loss<<<1, 1024, 0, stream>>>(partials, out, NB5);
    } else {
        float* partials = (float*)ws;
        dim3 grid(NBX, NBY, NBZ);
        fused_edge_loss<<<grid, 256, 0, stream>>>(score0, score1, target, partials);
        finalize_loss<<<1, 1024, 0, stream>>>(partials, out, NB);
    }
}